// Round 14
// baseline (146.965 us; speedup 1.0000x reference)
//
#include <hip/hip_runtime.h>
#include <hip/hip_bf16.h>

#define T 128
#define C 20
#define KQ 100
#define NT 256
#define SCALE 0.08838834764831845f   // 1/sqrt(128)
#define K2E   0.12751744f            // SCALE * log2(e)
#define LOG2E 1.4426950408889634f
#define TWOL2E 2.885390081777927f    // 2*log2(e), folded into Wv/bv in prep
#define KST 144    // kp8/q8 row stride: 36 dw == 4 mod 32 -> 2-way (free); 16B-aligned rows
#define VST 136    // vT8 row stride (34 dw, proven conflict-free); 20 rows only

typedef float  f32x4  __attribute__((ext_vector_type(4)));
typedef short  bf16x8 __attribute__((ext_vector_type(8)));
typedef long   lg2    __attribute__((ext_vector_type(2)));
typedef unsigned int uint32;

// single-instruction transcendentals via proper builtins (hazard-modeled).
__device__ __forceinline__ float exp2i(float x) { return __builtin_amdgcn_exp2f(x); }
__device__ __forceinline__ float rcpi(float x)  { return __builtin_amdgcn_rcpf(x); }

__device__ __forceinline__ short f2bf(float f) {
    unsigned u = __builtin_bit_cast(unsigned, f);
    unsigned r = (u + 0x7FFFu + ((u >> 16) & 1u)) >> 16;   // RNE
    return (short)r;
}
__device__ __forceinline__ uint32 pk2(float a, float b) {  // v_cvt_pk_bf16_f32
    __hip_bfloat162 h = __float22bfloat162_rn(float2{a, b});
    uint32 r;
    __builtin_memcpy(&r, &h, 4);
    return r;
}
__device__ __forceinline__ int pkfp8x4(float a, float b, float c, float d) {
    int r = __builtin_amdgcn_cvt_pk_fp8_f32(a, b, 0, false);   // bytes 0,1
    r = __builtin_amdgcn_cvt_pk_fp8_f32(c, d, r, true);        // bytes 2,3
    return r;
}
__device__ __forceinline__ unsigned char fp8_1(float a) {
    return (unsigned char)(__builtin_amdgcn_cvt_pk_fp8_f32(a, 0.f, 0, false) & 0xff);
}

// ---- prep: weights -> bf16 A-fragment tiles in d_ws, BIAS FOLDED at c==20 ----
// wAll = 16 tiles x [16 ch][32 c] bf16 (k:0..6, q:7..13, v:14..15).
// Row c=20 of each tile holds the bias (x fragment supplies 1.0 there).
// v weights pre-scaled by 2*log2(e) so tanh needs no input mul in-kernel.
__global__ void prep(const float* __restrict__ Wk, const float* __restrict__ bk,
                     const float* __restrict__ Wq, const float* __restrict__ bq,
                     const float* __restrict__ Wv, const float* __restrict__ bv,
                     short* __restrict__ wkT, short* __restrict__ wqT,
                     short* __restrict__ wvT)
{
    const int t = blockIdx.x * blockDim.x + threadIdx.x;
    if (t < 112 * 32) {
        const int n = t >> 5, c = t & 31;
        float vk = 0.f, vq = 0.f;
        if (n < KQ) {
            if (c < C)       { vk = Wk[c * KQ + n]; vq = Wq[c * KQ + n]; }
            else if (c == C) { vk = bk[n];          vq = bq[n]; }
        }
        wkT[t] = f2bf(vk);
        wqT[t] = f2bf(vq);
        if (t < 32 * 32) {
            const int n2 = t >> 5, c2 = t & 31;
            float vv = 0.f;
            if (n2 < C) {
                if (c2 < C)       vv = Wv[c2 * C + n2] * TWOL2E;
                else if (c2 == C) vv = bv[n2] * TWOL2E;
            }
            wvT[t] = f2bf(vv);
        }
    }
}

// R12 (2nd resubmit — two consecutive acquisition timeouts): halve DS issue
// count via channel-permuted storage. The fp8 MFMA fragment wants channels
// ks*32+quad*8+u; storing channel d at position p(d) = quad_of(d)*32 +
// ks(d)*8 + u(d) makes each thread's 4 K-slices 32 CONTIGUOUS bytes -> 2x
// ds_read_b128 replaces 4x ds_read_b64 (score 40->20, PV 16->12 reads/wave).
// KST=144 (16B-aligned rows so b128 is emitted; 36 dw = 2-way banking,
// free). LDS: vT8 shrinks to its 20 real rows (39,584 B total, still 4
// blocks/CU); PV nt=1 B-rows >=20 feed only discarded output cols (dd>=20)
// -> clamped address (MFMA is column-separable). Proj v-writes for dd>=20
// suppressed. Math bit-identical to R11 (absmax must stay 0.078125).
__global__ __launch_bounds__(NT, 4) void sa_fused(
    const float* __restrict__ x,
    const short* __restrict__ wAll,
    float* __restrict__ y)
{
    __shared__ __align__(16) unsigned char kp8[T * KST];    // k fp8 [i][p(d)] -> later 64*P [i][p(j)]
    __shared__ __align__(16) unsigned char q8 [T * KST];    // q fp8 [j][p(d)]
    __shared__ __align__(16) unsigned char vT8[20 * VST];   // v^T fp8 [dd][pos], 20 real rows

    const int tid  = threadIdx.x;
    const int lane = tid & 63;
    const int w    = __builtin_amdgcn_readfirstlane(tid >> 6);   // 0..3
    const int quad = lane >> 4;
    const int l16  = lane & 15;
    const int b    = blockIdx.x;
    const float* xb = x + (size_t)b * (T * C);
    const int qhi  = (quad >> 1) * 32 + (quad & 1) * 4;    // permuted quad offset

    // ---- issue x global loads FIRST (both row-tiles; latency overlaps pad) ----
    float4 fA[2], fB[2];
    #pragma unroll
    for (int h = 0; h < 2; ++h) {
        const float* xr = xb + ((w + 4 * h) * 16 + l16) * C;
        fA[h] = (float4){0.f, 0.f, 0.f, 0.f};
        fB[h] = (float4){0.f, 0.f, 0.f, 0.f};
        if (quad < 2) {
            fA[h] = *(const float4*)(xr + quad * 8);
            fB[h] = *(const float4*)(xr + quad * 8 + 4);
        } else if (quad == 2) {
            fA[h] = *(const float4*)(xr + 16);
        }
    }

    // ---- zero pad channels 112..127 -> permuted positions 88..95 & 120..127.
    //      (channels 96..111 are natural zeros via zeroed weight tile ct=6.) ----
    {
        const uint2 z = {0u, 0u};
        unsigned char* pb = (tid < T) ? kp8 : q8;
        const int prow = tid & (T - 1);
        *(uint2*)&pb[prow * KST + 88]  = z;
        *(uint2*)&pb[prow * KST + 120] = z;
    }

    // ---- x fragments (two i-tiles): c pad 20->32, c=20 element = 1.0 (bias) ----
    bf16x8 xf[2];
    #pragma unroll
    for (int h = 0; h < 2; ++h) {
        uint32 p0 = 0, p1 = 0, p2 = 0, p3 = 0;
        if (quad < 2) {
            p0 = pk2(fA[h].x, fA[h].y); p1 = pk2(fA[h].z, fA[h].w);
            p2 = pk2(fB[h].x, fB[h].y); p3 = pk2(fB[h].z, fB[h].w);
        } else if (quad == 2) {
            p0 = pk2(fA[h].x, fA[h].y); p1 = pk2(fA[h].z, fA[h].w);
            p2 = pk2(1.f, 0.f);                       // c=20 -> 1.0 (bias row)
        }
        uint4 u4; u4.x = p0; u4.y = p1; u4.z = p2; u4.w = p3;
        xf[h] = __builtin_bit_cast(bf16x8, u4);
    }

    // ---- projections (bf16 MFMA): wave w owns i-tiles w and w+4 ----
    #pragma unroll
    for (int grp = 0; grp < 4; ++grp) {
        bf16x8 wfr[4];
        #pragma unroll
        for (int t = 0; t < 4; ++t)
            wfr[t] = *(const bf16x8*)(wAll + ((grp * 4 + t) * 16 + l16) * 32 + quad * 8);
        #pragma unroll
        for (int s = 0; s < 4; ++s) {
            const int tt = grp * 4 + s;
            #pragma unroll
            for (int h = 0; h < 2; ++h) {
                const int row = (w + 4 * h) * 16 + l16;
                const f32x4 cc = __builtin_amdgcn_mfma_f32_16x16x32_bf16(
                    wfr[s], xf[h], (f32x4){0.f, 0.f, 0.f, 0.f}, 0, 0, 0);
                if (tt < 14) {                                    // k or q: ELU -> fp8 b32 write
                    float e[4];
                    #pragma unroll
                    for (int r = 0; r < 4; ++r) {
                        const float z = cc[r];
                        // ELU(z) = median(z, e^z-1, 0): e^z-1 >= z always.
                        e[r] = __builtin_amdgcn_fmed3f(z, exp2i(z * LOG2E) - 1.f, 0.f);
                    }
                    const int ct = (tt < 7) ? tt : tt - 7;        // compile-time
                    const int pbase = (ct & 1) * 64 + (ct >> 1) * 8 + qhi;  // permuted col
                    unsigned char* dst = (tt < 7)
                        ? &kp8[row * KST + pbase]
                        : &q8 [row * KST + pbase];
                    *(int*)dst = pkfp8x4(e[0], e[1], e[2], e[3]);
                } else {                                          // v: tanh -> vT scatter (b8)
                    // dd = (tt-14)*16 + quad*4 + r; only dd<20 stored (20-row vT8)
                    if (tt == 14 || quad == 0) {
                        #pragma unroll
                        for (int r = 0; r < 4; ++r) {
                            const float e2 = exp2i(cc[r]);        // cc pre-scaled 2log2e
                            vT8[((tt - 14) * 16 + quad * 4 + r) * VST + row]
                                = fp8_1(fmaf(-2.f, rcpi(e2 + 1.f), 1.f));
                        }
                    }
                }
            }
        }
    }
    __syncthreads();

    // ---- scores TRANSPOSED (fp8): S^T = q.k^T. Permuted layout: each
    //      thread's 4 K-slices are 32 contiguous bytes -> 2x b128 each. ----
    f32x4 acc[2][8];
    #pragma unroll
    for (int h = 0; h < 2; ++h)
        #pragma unroll
        for (int nt = 0; nt < 8; ++nt) acc[h][nt] = (f32x4){0.f, 0.f, 0.f, 0.f};
    __builtin_amdgcn_s_setprio(1);
    #pragma unroll
    for (int kp = 0; kp < 2; ++kp) {
        const lg2 a0 = __builtin_bit_cast(lg2,
            *(const uint4*)&q8[( w      * 16 + l16) * KST + quad * 32 + kp * 16]);
        const lg2 a1 = __builtin_bit_cast(lg2,
            *(const uint4*)&q8[((w + 4) * 16 + l16) * KST + quad * 32 + kp * 16]);
        #pragma unroll
        for (int nt = 0; nt < 8; ++nt) {
            const lg2 bb = __builtin_bit_cast(lg2,
                *(const uint4*)&kp8[(nt * 16 + l16) * KST + quad * 32 + kp * 16]);
            acc[0][nt] = __builtin_amdgcn_mfma_f32_16x16x32_fp8_fp8(a0.x, bb.x, acc[0][nt], 0, 0, 0);
            acc[0][nt] = __builtin_amdgcn_mfma_f32_16x16x32_fp8_fp8(a0.y, bb.y, acc[0][nt], 0, 0, 0);
            acc[1][nt] = __builtin_amdgcn_mfma_f32_16x16x32_fp8_fp8(a1.x, bb.x, acc[1][nt], 0, 0, 0);
            acc[1][nt] = __builtin_amdgcn_mfma_f32_16x16x32_fp8_fp8(a1.y, bb.y, acc[1][nt], 0, 0, 0);
        }
    }
    __builtin_amdgcn_s_setprio(0);

    // ---- softmax over i (axis=1), in registers, both j-tiles ----
    float ssum[2][4];
    #pragma unroll
    for (int h = 0; h < 2; ++h) {
        #pragma unroll
        for (int r = 0; r < 4; ++r) ssum[h][r] = 0.f;
        #pragma unroll
        for (int nt = 0; nt < 8; ++nt)
            #pragma unroll
            for (int r = 0; r < 4; ++r) {
                const float e = exp2i(acc[h][nt][r] * K2E);
                acc[h][nt][r] = e;
                ssum[h][r] += e;
            }
        #pragma unroll
        for (int r = 0; r < 4; ++r) {
            float s = ssum[h][r];
            s += __shfl_xor(s, 1); s += __shfl_xor(s, 2);
            s += __shfl_xor(s, 4); s += __shfl_xor(s, 8);
            ssum[h][r] = 64.f * rcpi(s);                          // 64*linv[j]
        }
    }
    __syncthreads();                                              // all score reads done

    // ---- write 64*P[i][p(j)] fp8 (b32), both tiles. pw(jt)=(jt&1)*64+(jt>>1)*8+qhi;
    //      jt=w and jt=w+4 differ by exactly +16. ----
    const int pw0 = (w & 1) * 64 + (w >> 1) * 8 + qhi;
    #pragma unroll
    for (int nt = 0; nt < 8; ++nt) {
        *(int*)&kp8[(nt * 16 + l16) * KST + pw0]
            = pkfp8x4(acc[0][nt][0] * ssum[0][0], acc[0][nt][1] * ssum[0][1],
                      acc[0][nt][2] * ssum[0][2], acc[0][nt][3] * ssum[0][3]);
        *(int*)&kp8[(nt * 16 + l16) * KST + pw0 + 16]
            = pkfp8x4(acc[1][nt][0] * ssum[1][0], acc[1][nt][1] * ssum[1][1],
                      acc[1][nt][2] * ssum[1][2], acc[1][nt][3] * ssum[1][3]);
    }
    __syncthreads();

    // ---- PV (fp8): A = 64P rows (2x b128 each), B = v^T b64 (20 real rows;
    //      nt=1 rows>=20 feed only discarded output cols dd>=20 -> clamp). ----
    f32x4 yacc[2][2];
    #pragma unroll
    for (int h = 0; h < 2; ++h) {
        yacc[h][0] = (f32x4){0.f, 0.f, 0.f, 0.f};
        yacc[h][1] = (f32x4){0.f, 0.f, 0.f, 0.f};
    }
    const int vr1 = (l16 < 4) ? 16 + l16 : l16;   // safe in-bounds row for nt=1
    __builtin_amdgcn_s_setprio(1);
    #pragma unroll
    for (int kp = 0; kp < 2; ++kp) {
        const lg2 a0 = __builtin_bit_cast(lg2,
            *(const uint4*)&kp8[( w      * 16 + l16) * KST + quad * 32 + kp * 16]);
        const lg2 a1 = __builtin_bit_cast(lg2,
            *(const uint4*)&kp8[((w + 4) * 16 + l16) * KST + quad * 32 + kp * 16]);
        #pragma unroll
        for (int nt = 0; nt < 2; ++nt) {
            const int rowv = nt ? vr1 : l16;
            const long b0 = *(const long*)&vT8[rowv * VST + (kp * 2    ) * 32 + quad * 8];
            const long b1 = *(const long*)&vT8[rowv * VST + (kp * 2 + 1) * 32 + quad * 8];
            yacc[0][nt] = __builtin_amdgcn_mfma_f32_16x16x32_fp8_fp8(a0.x, b0, yacc[0][nt], 0, 0, 0);
            yacc[0][nt] = __builtin_amdgcn_mfma_f32_16x16x32_fp8_fp8(a0.y, b1, yacc[0][nt], 0, 0, 0);
            yacc[1][nt] = __builtin_amdgcn_mfma_f32_16x16x32_fp8_fp8(a1.x, b0, yacc[1][nt], 0, 0, 0);
            yacc[1][nt] = __builtin_amdgcn_mfma_f32_16x16x32_fp8_fp8(a1.y, b1, yacc[1][nt], 0, 0, 0);
        }
    }
    __builtin_amdgcn_s_setprio(0);

    // ---- epilogue: y = PV/64 + x (direct stores; yacc[1] used only l16<4) ----
    {
        float* yb = y + (size_t)b * (T * C);
        const float inv64 = 1.f / 64.f;
        #pragma unroll
        for (int h = 0; h < 2; ++h)
            #pragma unroll
            for (int r = 0; r < 4; ++r) {
                const int row  = (w + 4 * h) * 16 + quad * 4 + r;
                const int base = row * C;
                yb[base + l16] = yacc[h][0][r] * inv64 + xb[base + l16];
                if (l16 < 4)
                    yb[base + 16 + l16] = yacc[h][1][r] * inv64 + xb[base + 16 + l16];
            }
    }
}

extern "C" void kernel_launch(void* const* d_in, const int* in_sizes, int n_in,
                              void* d_out, int out_size, void* d_ws, size_t ws_size,
                              hipStream_t stream) {
    const float* x  = (const float*)d_in[0];
    const float* Wk = (const float*)d_in[1];
    const float* bk = (const float*)d_in[2];
    const float* Wq = (const float*)d_in[3];
    const float* bq = (const float*)d_in[4];
    const float* Wv = (const float*)d_in[5];
    const float* bv = (const float*)d_in[6];
    float* y = (float*)d_out;

    char* ws = (char*)d_ws;
    short* wkT = (short*)ws;                 // tiles 0..6   [112][32] bf16 (bias at c=20)
    short* wqT = (short*)(ws + 7168);        // tiles 7..13  [112][32] bf16
    short* wvT = (short*)(ws + 14336);       // tiles 14..15 [32][32]  bf16 (pre-scaled 2log2e)

    prep<<<14, 256, 0, stream>>>(Wk, bk, Wq, bq, Wv, bv, wkT, wqT, wvT);

    const int B = in_sizes[0] / (T * C);     // 4096
    sa_fused<<<B, NT, 0, stream>>>(x, (const short*)ws, y);
}

// Round 15
// 144.394 us; speedup vs baseline: 1.0178x; 1.0178x over previous
//
#include <hip/hip_runtime.h>
#include <hip/hip_bf16.h>

#define T 128
#define C 20
#define KQ 100
#define NT 256
#define SCALE 0.08838834764831845f   // 1/sqrt(128)
#define K2E   0.12751744f            // SCALE * log2(e)
#define LOG2E 1.4426950408889634f
#define TWOL2E 2.885390081777927f    // 2*log2(e), folded into Wv/bv in prep
#define LDS8 136   // fp8 row stride (bytes): 34 dw -> b64 reads land 1-way (banks {2r,2r+1})

typedef float  f32x4  __attribute__((ext_vector_type(4)));
typedef short  bf16x8 __attribute__((ext_vector_type(8)));
typedef unsigned int uint32;

// single-instruction transcendentals via proper builtins (hazard-modeled).
__device__ __forceinline__ float exp2i(float x) { return __builtin_amdgcn_exp2f(x); }
__device__ __forceinline__ float rcpi(float x)  { return __builtin_amdgcn_rcpf(x); }

__device__ __forceinline__ short f2bf(float f) {
    unsigned u = __builtin_bit_cast(unsigned, f);
    unsigned r = (u + 0x7FFFu + ((u >> 16) & 1u)) >> 16;   // RNE
    return (short)r;
}
__device__ __forceinline__ uint32 pk2(float a, float b) {  // v_cvt_pk_bf16_f32
    __hip_bfloat162 h = __float22bfloat162_rn(float2{a, b});
    uint32 r;
    __builtin_memcpy(&r, &h, 4);
    return r;
}
__device__ __forceinline__ int pkfp8x4(float a, float b, float c, float d) {
    int r = __builtin_amdgcn_cvt_pk_fp8_f32(a, b, 0, false);   // bytes 0,1
    r = __builtin_amdgcn_cvt_pk_fp8_f32(c, d, r, true);        // bytes 2,3
    return r;
}
__device__ __forceinline__ unsigned char fp8_1(float a) {
    return (unsigned char)(__builtin_amdgcn_cvt_pk_fp8_f32(a, 0.f, 0, false) & 0xff);
}

// ---- prep: weights -> bf16 A-fragment tiles in d_ws, BIAS FOLDED at c==20 ----
// wAll = 16 tiles x [16 ch][32 c] bf16 (k:0..6, q:7..13, v:14..15).
// Row c=20 of each tile holds the bias (x fragment supplies 1.0 there).
// v weights pre-scaled by 2*log2(e) so tanh needs no input mul in-kernel.
__global__ void prep(const float* __restrict__ Wk, const float* __restrict__ bk,
                     const float* __restrict__ Wq, const float* __restrict__ bq,
                     const float* __restrict__ Wv, const float* __restrict__ bv,
                     short* __restrict__ wkT, short* __restrict__ wqT,
                     short* __restrict__ wvT)
{
    const int t = blockIdx.x * blockDim.x + threadIdx.x;
    if (t < 112 * 32) {
        const int n = t >> 5, c = t & 31;
        float vk = 0.f, vq = 0.f;
        if (n < KQ) {
            if (c < C)       { vk = Wk[c * KQ + n]; vq = Wq[c * KQ + n]; }
            else if (c == C) { vk = bk[n];          vq = bq[n]; }
        }
        wkT[t] = f2bf(vk);
        wqT[t] = f2bf(vq);
        if (t < 32 * 32) {
            const int n2 = t >> 5, c2 = t & 31;
            float vv = 0.f;
            if (n2 < C) {
                if (c2 < C)       vv = Wv[c2 * C + n2] * TWOL2E;
                else if (c2 == C) vv = bv[n2] * TWOL2E;
            }
            wvT[t] = f2bf(vv);
        }
    }
}

// R15 (final): revert to R11, the session's measured optimum (64.8-66.1 us/
// dispatch, 143.6 us total; conflicts 0, 4 blocks/CU, FETCH 21.8 MB).
// Failure catalog (each measured, mechanism identified):
//   R8  128-stride + partial swizzle -> 4.0M bank conflicts (row term = 0 mod 32)
//   R9  5 blocks/CU (stride 104)     -> HBM 3x (L2/L3 inter-block locality lost)
//   R10 x-residual reg preload       -> scratch spills (+270 MB; allocator sticky at 64 VGPR)
//   R12 b128 channel-permute (KST=144)-> 3.1M conflicts (b128 on 16 lanes is
//        inherently >=2-way; only b64 @ 34-dw stride is 1-way-perfect). Net -1.5%.
// Equilibrium: issue-bound (VALU-busy ~44 us invariant; VALU 66% + MFMA 18%
// at the max-locality occupancy). Remaining instructions are algorithmically
// minimal (100 ELU + 64 exp + 20 tanh per thread).
__global__ __launch_bounds__(NT, 4) void sa_fused(
    const float* __restrict__ x,
    const short* __restrict__ wAll,
    float* __restrict__ y)
{
    __shared__ __align__(16) unsigned char kp8[T * LDS8];   // k fp8 [i][d] -> later 64*P [i][j]
    __shared__ __align__(16) unsigned char q8 [T * LDS8];   // q fp8 [j][d]
    __shared__ __align__(16) unsigned char vT8[32 * LDS8];  // v^T fp8 [dd][pos] (rows 20..31 = 0)

    const int tid  = threadIdx.x;
    const int lane = tid & 63;
    const int w    = __builtin_amdgcn_readfirstlane(tid >> 6);   // 0..3
    const int quad = lane >> 4;
    const int l16  = lane & 15;
    const int b    = blockIdx.x;
    const float* xb = x + (size_t)b * (T * C);

    // ---- issue x global loads FIRST (both row-tiles; latency overlaps pad) ----
    float4 fA[2], fB[2];
    #pragma unroll
    for (int h = 0; h < 2; ++h) {
        const float* xr = xb + ((w + 4 * h) * 16 + l16) * C;
        fA[h] = (float4){0.f, 0.f, 0.f, 0.f};
        fB[h] = (float4){0.f, 0.f, 0.f, 0.f};
        if (quad < 2) {
            fA[h] = *(const float4*)(xr + quad * 8);
            fB[h] = *(const float4*)(xr + quad * 8 + 4);
        } else if (quad == 2) {
            fA[h] = *(const float4*)(xr + 16);
        }
    }

    // ---- zero pad cols 112..127 of kp8/q8 (d-tail read by score K-loop).
    //      All 256 threads, one uint4 each: tid<128 -> kp8, tid>=128 -> q8. ----
    {
        const uint4 z4 = {0u, 0u, 0u, 0u};
        unsigned char* pb = (tid < T) ? kp8 : q8;
        *(uint4*)&pb[(tid & (T - 1)) * LDS8 + 112] = z4;
    }

    // ---- x fragments (two i-tiles): A[m=l16][k=quad*8+u] == B[k][n=l16];
    //      c pad 20->32, with c=20 element = 1.0 (bias row multiplier) ----
    bf16x8 xf[2];
    #pragma unroll
    for (int h = 0; h < 2; ++h) {
        uint32 p0 = 0, p1 = 0, p2 = 0, p3 = 0;
        if (quad < 2) {
            p0 = pk2(fA[h].x, fA[h].y); p1 = pk2(fA[h].z, fA[h].w);
            p2 = pk2(fB[h].x, fB[h].y); p3 = pk2(fB[h].z, fB[h].w);
        } else if (quad == 2) {
            p0 = pk2(fA[h].x, fA[h].y); p1 = pk2(fA[h].z, fA[h].w);
            p2 = pk2(1.f, 0.f);                       // c=20 -> 1.0 (bias row)
        }
        uint4 u4; u4.x = p0; u4.y = p1; u4.z = p2; u4.w = p3;
        xf[h] = __builtin_bit_cast(bf16x8, u4);
    }

    // ---- projections (bf16 MFMA): wave w owns i-tiles w and w+4. Weight
    //      fragments loaded once per group, used by both tiles. ----
    #pragma unroll
    for (int grp = 0; grp < 4; ++grp) {
        bf16x8 wfr[4];
        #pragma unroll
        for (int t = 0; t < 4; ++t)
            wfr[t] = *(const bf16x8*)(wAll + ((grp * 4 + t) * 16 + l16) * 32 + quad * 8);
        #pragma unroll
        for (int s = 0; s < 4; ++s) {
            const int tt = grp * 4 + s;
            #pragma unroll
            for (int h = 0; h < 2; ++h) {
                const int row = (w + 4 * h) * 16 + l16;
                const f32x4 cc = __builtin_amdgcn_mfma_f32_16x16x32_bf16(
                    wfr[s], xf[h], (f32x4){0.f, 0.f, 0.f, 0.f}, 0, 0, 0);
                if (tt < 14) {                                    // k or q: ELU -> fp8 b32 write
                    float e[4];
                    #pragma unroll
                    for (int r = 0; r < 4; ++r) {
                        const float z = cc[r];
                        // ELU(z) = median(z, e^z-1, 0): e^z-1 >= z always.
                        e[r] = __builtin_amdgcn_fmed3f(z, exp2i(z * LOG2E) - 1.f, 0.f);
                    }
                    unsigned char* dst = (tt < 7)
                        ? &kp8[row * LDS8 + tt * 16 + quad * 4]
                        : &q8 [row * LDS8 + (tt - 7) * 16 + quad * 4];
                    *(int*)dst = pkfp8x4(e[0], e[1], e[2], e[3]);
                } else {                                          // v: tanh -> vT scatter (b8)
                    #pragma unroll
                    for (int r = 0; r < 4; ++r) {
                        // cc already = 2*log2e*(xWv+bv) via prep pre-scale
                        const float e2 = exp2i(cc[r]);
                        vT8[((tt - 14) * 16 + quad * 4 + r) * LDS8 + row]
                            = fp8_1(fmaf(-2.f, rcpi(e2 + 1.f), 1.f));
                    }
                }
            }
        }
    }
    __syncthreads();

    // ---- scores TRANSPOSED (fp8): S^T = q.k^T. Two j-tiles per wave;
    //      B-operand (k rows) read once, feeds both streams. ----
    f32x4 acc[2][8];
    #pragma unroll
    for (int h = 0; h < 2; ++h)
        #pragma unroll
        for (int nt = 0; nt < 8; ++nt) acc[h][nt] = (f32x4){0.f, 0.f, 0.f, 0.f};
    __builtin_amdgcn_s_setprio(1);
    #pragma unroll
    for (int ks = 0; ks < 4; ++ks) {
        const long a0 = *(const long*)&q8[( w      * 16 + l16) * LDS8 + ks * 32 + quad * 8];
        const long a1 = *(const long*)&q8[((w + 4) * 16 + l16) * LDS8 + ks * 32 + quad * 8];
        #pragma unroll
        for (int nt = 0; nt < 8; ++nt) {
            const long bk8 = *(const long*)&kp8[(nt * 16 + l16) * LDS8 + ks * 32 + quad * 8];
            acc[0][nt] = __builtin_amdgcn_mfma_f32_16x16x32_fp8_fp8(a0, bk8, acc[0][nt], 0, 0, 0);
            acc[1][nt] = __builtin_amdgcn_mfma_f32_16x16x32_fp8_fp8(a1, bk8, acc[1][nt], 0, 0, 0);
        }
    }
    __builtin_amdgcn_s_setprio(0);

    // ---- softmax over i (axis=1), in registers, both j-tiles ----
    float ssum[2][4];
    #pragma unroll
    for (int h = 0; h < 2; ++h) {
        #pragma unroll
        for (int r = 0; r < 4; ++r) ssum[h][r] = 0.f;
        #pragma unroll
        for (int nt = 0; nt < 8; ++nt)
            #pragma unroll
            for (int r = 0; r < 4; ++r) {
                const float e = exp2i(acc[h][nt][r] * K2E);
                acc[h][nt][r] = e;
                ssum[h][r] += e;
            }
        #pragma unroll
        for (int r = 0; r < 4; ++r) {
            float s = ssum[h][r];
            s += __shfl_xor(s, 1); s += __shfl_xor(s, 2);
            s += __shfl_xor(s, 4); s += __shfl_xor(s, 8);
            ssum[h][r] = 64.f * rcpi(s);                          // 64*linv[j]
        }
    }
    __syncthreads();                                              // all score reads of kp8/q8 done

    // ---- write 64*P[i][j] fp8 (b32: 4 consecutive j per thread) both tiles ----
    #pragma unroll
    for (int nt = 0; nt < 8; ++nt) {
        *(int*)&kp8[(nt * 16 + l16) * LDS8 + w * 16 + quad * 4]
            = pkfp8x4(acc[0][nt][0] * ssum[0][0], acc[0][nt][1] * ssum[0][1],
                      acc[0][nt][2] * ssum[0][2], acc[0][nt][3] * ssum[0][3]);
        *(int*)&kp8[(nt * 16 + l16) * LDS8 + (w + 4) * 16 + quad * 4]
            = pkfp8x4(acc[1][nt][0] * ssum[1][0], acc[1][nt][1] * ssum[1][1],
                      acc[1][nt][2] * ssum[1][2], acc[1][nt][3] * ssum[1][3]);
    }
    __syncthreads();

    // ---- PV (fp8): A = 64P rows (two i-tiles), B = v^T (N = 32, shared) ----
    f32x4 yacc[2][2];
    #pragma unroll
    for (int h = 0; h < 2; ++h) {
        yacc[h][0] = (f32x4){0.f, 0.f, 0.f, 0.f};
        yacc[h][1] = (f32x4){0.f, 0.f, 0.f, 0.f};
    }
    __builtin_amdgcn_s_setprio(1);
    #pragma unroll
    for (int ks = 0; ks < 4; ++ks) {
        const long a0 = *(const long*)&kp8[( w      * 16 + l16) * LDS8 + ks * 32 + quad * 8];
        const long a1 = *(const long*)&kp8[((w + 4) * 16 + l16) * LDS8 + ks * 32 + quad * 8];
        #pragma unroll
        for (int nt = 0; nt < 2; ++nt) {
            const long bv8 = *(const long*)&vT8[(nt * 16 + l16) * LDS8 + ks * 32 + quad * 8];
            yacc[0][nt] = __builtin_amdgcn_mfma_f32_16x16x32_fp8_fp8(a0, bv8, yacc[0][nt], 0, 0, 0);
            yacc[1][nt] = __builtin_amdgcn_mfma_f32_16x16x32_fp8_fp8(a1, bv8, yacc[1][nt], 0, 0, 0);
        }
    }
    __builtin_amdgcn_s_setprio(0);

    // ---- epilogue: y = PV/64 + x (direct stores, R7-known-good) ----
    {
        float* yb = y + (size_t)b * (T * C);
        const float inv64 = 1.f / 64.f;
        #pragma unroll
        for (int h = 0; h < 2; ++h)
            #pragma unroll
            for (int r = 0; r < 4; ++r) {
                const int row  = (w + 4 * h) * 16 + quad * 4 + r;
                const int base = row * C;
                yb[base + l16] = yacc[h][0][r] * inv64 + xb[base + l16];
                if (l16 < 4)
                    yb[base + 16 + l16] = yacc[h][1][r] * inv64 + xb[base + 16 + l16];
            }
    }
}

extern "C" void kernel_launch(void* const* d_in, const int* in_sizes, int n_in,
                              void* d_out, int out_size, void* d_ws, size_t ws_size,
                              hipStream_t stream) {
    const float* x  = (const float*)d_in[0];
    const float* Wk = (const float*)d_in[1];
    const float* bk = (const float*)d_in[2];
    const float* Wq = (const float*)d_in[3];
    const float* bq = (const float*)d_in[4];
    const float* Wv = (const float*)d_in[5];
    const float* bv = (const float*)d_in[6];
    float* y = (float*)d_out;

    char* ws = (char*)d_ws;
    short* wkT = (short*)ws;                 // tiles 0..6   [112][32] bf16 (bias at c=20)
    short* wqT = (short*)(ws + 7168);        // tiles 7..13  [112][32] bf16
    short* wvT = (short*)(ws + 14336);       // tiles 14..15 [32][32]  bf16 (pre-scaled 2log2e)

    prep<<<14, 256, 0, stream>>>(Wk, bk, Wq, bq, Wv, bv, wkT, wqT, wvT);

    const int B = in_sizes[0] / (T * C);     // 4096
    sa_fused<<<B, NT, 0, stream>>>(x, (const short*)ws, y);
}

// Round 16
// 142.550 us; speedup vs baseline: 1.0310x; 1.0129x over previous
//
#include <hip/hip_runtime.h>
#include <hip/hip_bf16.h>

#define T 128
#define C 20
#define KQ 100
#define NT 256
#define SCALE 0.08838834764831845f   // 1/sqrt(128)
#define K2E   0.12751744f            // SCALE * log2(e)
#define LOG2E 1.4426950408889634f
#define TWOL2E 2.885390081777927f    // 2*log2(e), folded into Wv/bv in prep
#define LDS8 136   // fp8 row stride (bytes): 34 dw -> b64 reads land 1-way (banks {2r,2r+1})

typedef float  f32x4  __attribute__((ext_vector_type(4)));
typedef float  f32x2  __attribute__((ext_vector_type(2)));
typedef short  bf16x8 __attribute__((ext_vector_type(8)));
typedef unsigned int uint32;

// single-instruction transcendentals via proper builtins (hazard-modeled).
__device__ __forceinline__ float exp2i(float x) { return __builtin_amdgcn_exp2f(x); }
__device__ __forceinline__ float rcpi(float x)  { return __builtin_amdgcn_rcpf(x); }

__device__ __forceinline__ short f2bf(float f) {
    unsigned u = __builtin_bit_cast(unsigned, f);
    unsigned r = (u + 0x7FFFu + ((u >> 16) & 1u)) >> 16;   // RNE
    return (short)r;
}
__device__ __forceinline__ uint32 pk2(float a, float b) {  // v_cvt_pk_bf16_f32
    __hip_bfloat162 h = __float22bfloat162_rn(float2{a, b});
    uint32 r;
    __builtin_memcpy(&r, &h, 4);
    return r;
}
__device__ __forceinline__ int pkfp8x4(float a, float b, float c, float d) {
    int r = __builtin_amdgcn_cvt_pk_fp8_f32(a, b, 0, false);   // bytes 0,1
    r = __builtin_amdgcn_cvt_pk_fp8_f32(c, d, r, true);        // bytes 2,3
    return r;
}
__device__ __forceinline__ unsigned char fp8_1(float a) {
    return (unsigned char)(__builtin_amdgcn_cvt_pk_fp8_f32(a, 0.f, 0, false) & 0xff);
}

// ---- prep: weights -> bf16 A-fragment tiles in d_ws, BIAS FOLDED at c==20 ----
// wAll = 16 tiles x [16 ch][32 c] bf16 (k:0..6, q:7..13, v:14..15).
// Row c=20 of each tile holds the bias (x fragment supplies 1.0 there).
// v weights pre-scaled by 2*log2(e) so tanh needs no input mul in-kernel.
__global__ void prep(const float* __restrict__ Wk, const float* __restrict__ bk,
                     const float* __restrict__ Wq, const float* __restrict__ bq,
                     const float* __restrict__ Wv, const float* __restrict__ bv,
                     short* __restrict__ wkT, short* __restrict__ wqT,
                     short* __restrict__ wvT)
{
    const int t = blockIdx.x * blockDim.x + threadIdx.x;
    if (t < 112 * 32) {
        const int n = t >> 5, c = t & 31;
        float vk = 0.f, vq = 0.f;
        if (n < KQ) {
            if (c < C)       { vk = Wk[c * KQ + n]; vq = Wq[c * KQ + n]; }
            else if (c == C) { vk = bk[n];          vq = bq[n]; }
        }
        wkT[t] = f2bf(vk);
        wqT[t] = f2bf(vq);
        if (t < 32 * 32) {
            const int n2 = t >> 5, c2 = t & 31;
            float vv = 0.f;
            if (n2 < C) {
                if (c2 < C)       vv = Wv[c2 * C + n2] * TWOL2E;
                else if (c2 == C) vv = bv[n2] * TWOL2E;
            }
            wvT[t] = f2bf(vv);
        }
    }
}

// R16: R15 reproduced the R11 optimum (64.8-66.2 us, issue-bound: VALU-busy
// ~44 us invariant, conflicts 0, 4 blocks/CU max-locality). Last lever on the
// instruction count: packed f32 VALU (v_pk_mul/add_f32, CDNA4 dual f32) for
// the non-transcendental halo — ELU's z*LOG2E muls and -1 subs, softmax's
// K2E muls + ssum adds, P-write's acc*ssum muls: ~208 fewer VALU issues
// (~19% of VALU cycles). exp/rcp/med3 stay scalar (TRANS/VOP3). Arithmetic
// bit-identical per element (absmax must stay 0.078125). If the backend
// scalarizes the <2 x float> ops, change is a harmless null.
__global__ __launch_bounds__(NT, 4) void sa_fused(
    const float* __restrict__ x,
    const short* __restrict__ wAll,
    float* __restrict__ y)
{
    __shared__ __align__(16) unsigned char kp8[T * LDS8];   // k fp8 [i][d] -> later 64*P [i][j]
    __shared__ __align__(16) unsigned char q8 [T * LDS8];   // q fp8 [j][d]
    __shared__ __align__(16) unsigned char vT8[32 * LDS8];  // v^T fp8 [dd][pos] (rows 20..31 = 0)

    const int tid  = threadIdx.x;
    const int lane = tid & 63;
    const int w    = __builtin_amdgcn_readfirstlane(tid >> 6);   // 0..3
    const int quad = lane >> 4;
    const int l16  = lane & 15;
    const int b    = blockIdx.x;
    const float* xb = x + (size_t)b * (T * C);

    // ---- issue x global loads FIRST (both row-tiles; latency overlaps pad) ----
    float4 fA[2], fB[2];
    #pragma unroll
    for (int h = 0; h < 2; ++h) {
        const float* xr = xb + ((w + 4 * h) * 16 + l16) * C;
        fA[h] = (float4){0.f, 0.f, 0.f, 0.f};
        fB[h] = (float4){0.f, 0.f, 0.f, 0.f};
        if (quad < 2) {
            fA[h] = *(const float4*)(xr + quad * 8);
            fB[h] = *(const float4*)(xr + quad * 8 + 4);
        } else if (quad == 2) {
            fA[h] = *(const float4*)(xr + 16);
        }
    }

    // ---- zero pad cols 112..127 of kp8/q8 (d-tail read by score K-loop).
    //      All 256 threads, one uint4 each: tid<128 -> kp8, tid>=128 -> q8. ----
    {
        const uint4 z4 = {0u, 0u, 0u, 0u};
        unsigned char* pb = (tid < T) ? kp8 : q8;
        *(uint4*)&pb[(tid & (T - 1)) * LDS8 + 112] = z4;
    }

    // ---- x fragments (two i-tiles): A[m=l16][k=quad*8+u] == B[k][n=l16];
    //      c pad 20->32, with c=20 element = 1.0 (bias row multiplier) ----
    bf16x8 xf[2];
    #pragma unroll
    for (int h = 0; h < 2; ++h) {
        uint32 p0 = 0, p1 = 0, p2 = 0, p3 = 0;
        if (quad < 2) {
            p0 = pk2(fA[h].x, fA[h].y); p1 = pk2(fA[h].z, fA[h].w);
            p2 = pk2(fB[h].x, fB[h].y); p3 = pk2(fB[h].z, fB[h].w);
        } else if (quad == 2) {
            p0 = pk2(fA[h].x, fA[h].y); p1 = pk2(fA[h].z, fA[h].w);
            p2 = pk2(1.f, 0.f);                       // c=20 -> 1.0 (bias row)
        }
        uint4 u4; u4.x = p0; u4.y = p1; u4.z = p2; u4.w = p3;
        xf[h] = __builtin_bit_cast(bf16x8, u4);
    }

    // ---- projections (bf16 MFMA): wave w owns i-tiles w and w+4. Weight
    //      fragments loaded once per group, used by both tiles. ----
    #pragma unroll
    for (int grp = 0; grp < 4; ++grp) {
        bf16x8 wfr[4];
        #pragma unroll
        for (int t = 0; t < 4; ++t)
            wfr[t] = *(const bf16x8*)(wAll + ((grp * 4 + t) * 16 + l16) * 32 + quad * 8);
        #pragma unroll
        for (int s = 0; s < 4; ++s) {
            const int tt = grp * 4 + s;
            #pragma unroll
            for (int h = 0; h < 2; ++h) {
                const int row = (w + 4 * h) * 16 + l16;
                const f32x4 cc = __builtin_amdgcn_mfma_f32_16x16x32_bf16(
                    wfr[s], xf[h], (f32x4){0.f, 0.f, 0.f, 0.f}, 0, 0, 0);
                if (tt < 14) {                                    // k or q: ELU -> fp8 b32 write
                    // ELU(z) = median(z, e^z-1, 0); muls and -1 adds packed.
                    const f32x2 l2e2 = {LOG2E, LOG2E};
                    const f32x2 m1   = {-1.f, -1.f};
                    f32x2 elo = (f32x2){cc[0], cc[1]} * l2e2;     // v_pk_mul_f32
                    f32x2 ehi = (f32x2){cc[2], cc[3]} * l2e2;
                    elo.x = exp2i(elo.x); elo.y = exp2i(elo.y);
                    ehi.x = exp2i(ehi.x); ehi.y = exp2i(ehi.y);
                    elo += m1; ehi += m1;                         // v_pk_add_f32
                    float e[4];
                    e[0] = __builtin_amdgcn_fmed3f(cc[0], elo.x, 0.f);
                    e[1] = __builtin_amdgcn_fmed3f(cc[1], elo.y, 0.f);
                    e[2] = __builtin_amdgcn_fmed3f(cc[2], ehi.x, 0.f);
                    e[3] = __builtin_amdgcn_fmed3f(cc[3], ehi.y, 0.f);
                    unsigned char* dst = (tt < 7)
                        ? &kp8[row * LDS8 + tt * 16 + quad * 4]
                        : &q8 [row * LDS8 + (tt - 7) * 16 + quad * 4];
                    *(int*)dst = pkfp8x4(e[0], e[1], e[2], e[3]);
                } else {                                          // v: tanh -> vT scatter (b8)
                    #pragma unroll
                    for (int r = 0; r < 4; ++r) {
                        // cc already = 2*log2e*(xWv+bv) via prep pre-scale
                        const float e2 = exp2i(cc[r]);
                        vT8[((tt - 14) * 16 + quad * 4 + r) * LDS8 + row]
                            = fp8_1(fmaf(-2.f, rcpi(e2 + 1.f), 1.f));
                    }
                }
            }
        }
    }
    __syncthreads();

    // ---- scores TRANSPOSED (fp8): S^T = q.k^T. Two j-tiles per wave;
    //      B-operand (k rows) read once, feeds both streams. ----
    f32x4 acc[2][8];
    #pragma unroll
    for (int h = 0; h < 2; ++h)
        #pragma unroll
        for (int nt = 0; nt < 8; ++nt) acc[h][nt] = (f32x4){0.f, 0.f, 0.f, 0.f};
    __builtin_amdgcn_s_setprio(1);
    #pragma unroll
    for (int ks = 0; ks < 4; ++ks) {
        const long a0 = *(const long*)&q8[( w      * 16 + l16) * LDS8 + ks * 32 + quad * 8];
        const long a1 = *(const long*)&q8[((w + 4) * 16 + l16) * LDS8 + ks * 32 + quad * 8];
        #pragma unroll
        for (int nt = 0; nt < 8; ++nt) {
            const long bk8 = *(const long*)&kp8[(nt * 16 + l16) * LDS8 + ks * 32 + quad * 8];
            acc[0][nt] = __builtin_amdgcn_mfma_f32_16x16x32_fp8_fp8(a0, bk8, acc[0][nt], 0, 0, 0);
            acc[1][nt] = __builtin_amdgcn_mfma_f32_16x16x32_fp8_fp8(a1, bk8, acc[1][nt], 0, 0, 0);
        }
    }
    __builtin_amdgcn_s_setprio(0);

    // ---- softmax over i (axis=1), in registers, both j-tiles.
    //      K2E muls and ssum accumulates packed (exp stays scalar TRANS). ----
    float ssum[2][4];
    #pragma unroll
    for (int h = 0; h < 2; ++h) {
        const f32x2 k2e2 = {K2E, K2E};
        f32x2 sa = {0.f, 0.f}, sb = {0.f, 0.f};
        #pragma unroll
        for (int nt = 0; nt < 8; ++nt) {
            f32x2 plo = (f32x2){acc[h][nt][0], acc[h][nt][1]} * k2e2;   // v_pk_mul
            f32x2 phi = (f32x2){acc[h][nt][2], acc[h][nt][3]} * k2e2;
            plo.x = exp2i(plo.x); plo.y = exp2i(plo.y);
            phi.x = exp2i(phi.x); phi.y = exp2i(phi.y);
            acc[h][nt][0] = plo.x; acc[h][nt][1] = plo.y;
            acc[h][nt][2] = phi.x; acc[h][nt][3] = phi.y;
            sa += plo; sb += phi;                                       // v_pk_add
        }
        float st[4] = {sa.x, sa.y, sb.x, sb.y};
        #pragma unroll
        for (int r = 0; r < 4; ++r) {
            float s = st[r];
            s += __shfl_xor(s, 1); s += __shfl_xor(s, 2);
            s += __shfl_xor(s, 4); s += __shfl_xor(s, 8);
            ssum[h][r] = 64.f * rcpi(s);                          // 64*linv[j]
        }
    }
    __syncthreads();                                              // all score reads of kp8/q8 done

    // ---- write 64*P[i][j] fp8 (b32), both tiles; acc*ssum products packed ----
    {
        const f32x2 sA0 = {ssum[0][0], ssum[0][1]}, sB0 = {ssum[0][2], ssum[0][3]};
        const f32x2 sA1 = {ssum[1][0], ssum[1][1]}, sB1 = {ssum[1][2], ssum[1][3]};
        #pragma unroll
        for (int nt = 0; nt < 8; ++nt) {
            const f32x2 p0 = (f32x2){acc[0][nt][0], acc[0][nt][1]} * sA0;
            const f32x2 q0 = (f32x2){acc[0][nt][2], acc[0][nt][3]} * sB0;
            const f32x2 p1 = (f32x2){acc[1][nt][0], acc[1][nt][1]} * sA1;
            const f32x2 q1 = (f32x2){acc[1][nt][2], acc[1][nt][3]} * sB1;
            *(int*)&kp8[(nt * 16 + l16) * LDS8 + w * 16 + quad * 4]
                = pkfp8x4(p0.x, p0.y, q0.x, q0.y);
            *(int*)&kp8[(nt * 16 + l16) * LDS8 + (w + 4) * 16 + quad * 4]
                = pkfp8x4(p1.x, p1.y, q1.x, q1.y);
        }
    }
    __syncthreads();

    // ---- PV (fp8): A = 64P rows (two i-tiles), B = v^T (N = 32, shared) ----
    f32x4 yacc[2][2];
    #pragma unroll
    for (int h = 0; h < 2; ++h) {
        yacc[h][0] = (f32x4){0.f, 0.f, 0.f, 0.f};
        yacc[h][1] = (f32x4){0.f, 0.f, 0.f, 0.f};
    }
    __builtin_amdgcn_s_setprio(1);
    #pragma unroll
    for (int ks = 0; ks < 4; ++ks) {
        const long a0 = *(const long*)&kp8[( w      * 16 + l16) * LDS8 + ks * 32 + quad * 8];
        const long a1 = *(const long*)&kp8[((w + 4) * 16 + l16) * LDS8 + ks * 32 + quad * 8];
        #pragma unroll
        for (int nt = 0; nt < 2; ++nt) {
            const long bv8 = *(const long*)&vT8[(nt * 16 + l16) * LDS8 + ks * 32 + quad * 8];
            yacc[0][nt] = __builtin_amdgcn_mfma_f32_16x16x32_fp8_fp8(a0, bv8, yacc[0][nt], 0, 0, 0);
            yacc[1][nt] = __builtin_amdgcn_mfma_f32_16x16x32_fp8_fp8(a1, bv8, yacc[1][nt], 0, 0, 0);
        }
    }
    __builtin_amdgcn_s_setprio(0);

    // ---- epilogue: y = PV/64 + x (direct stores, R7-known-good) ----
    {
        float* yb = y + (size_t)b * (T * C);
        const float inv64 = 1.f / 64.f;
        #pragma unroll
        for (int h = 0; h < 2; ++h)
            #pragma unroll
            for (int r = 0; r < 4; ++r) {
                const int row  = (w + 4 * h) * 16 + quad * 4 + r;
                const int base = row * C;
                yb[base + l16] = yacc[h][0][r] * inv64 + xb[base + l16];
                if (l16 < 4)
                    yb[base + 16 + l16] = yacc[h][1][r] * inv64 + xb[base + 16 + l16];
            }
    }
}

extern "C" void kernel_launch(void* const* d_in, const int* in_sizes, int n_in,
                              void* d_out, int out_size, void* d_ws, size_t ws_size,
                              hipStream_t stream) {
    const float* x  = (const float*)d_in[0];
    const float* Wk = (const float*)d_in[1];
    const float* bk = (const float*)d_in[2];
    const float* Wq = (const float*)d_in[3];
    const float* bq = (const float*)d_in[4];
    const float* Wv = (const float*)d_in[5];
    const float* bv = (const float*)d_in[6];
    float* y = (float*)d_out;

    char* ws = (char*)d_ws;
    short* wkT = (short*)ws;                 // tiles 0..6   [112][32] bf16 (bias at c=20)
    short* wqT = (short*)(ws + 7168);        // tiles 7..13  [112][32] bf16
    short* wvT = (short*)(ws + 14336);       // tiles 14..15 [32][32]  bf16 (pre-scaled 2log2e)

    prep<<<14, 256, 0, stream>>>(Wk, bk, Wq, bq, Wv, bv, wkT, wqT, wvT);

    const int B = in_sizes[0] / (T * C);     // 4096
    sa_fused<<<B, NT, 0, stream>>>(x, (const short*)ws, y);
}

// Round 20
// 141.811 us; speedup vs baseline: 1.0363x; 1.0052x over previous
//
#include <hip/hip_runtime.h>
#include <hip/hip_bf16.h>

#define T 128
#define C 20
#define KQ 100
#define NT 256
#define SCALE 0.08838834764831845f   // 1/sqrt(128)
#define K2E   0.12751744f            // SCALE * log2(e)
#define LOG2E 1.4426950408889634f
#define TWOL2E 2.885390081777927f    // 2*log2(e), folded into Wv/bv in prep
#define LDS8 136   // fp8 row stride (bytes): 34 dw -> b64 reads land 1-way (banks {2r,2r+1})

typedef float  f32x4  __attribute__((ext_vector_type(4)));
typedef float  f32x2  __attribute__((ext_vector_type(2)));
typedef short  bf16x8 __attribute__((ext_vector_type(8)));
typedef unsigned int uint32;

// single-instruction transcendentals via proper builtins (hazard-modeled).
__device__ __forceinline__ float exp2i(float x) { return __builtin_amdgcn_exp2f(x); }
__device__ __forceinline__ float rcpi(float x)  { return __builtin_amdgcn_rcpf(x); }

__device__ __forceinline__ short f2bf(float f) {
    unsigned u = __builtin_bit_cast(unsigned, f);
    unsigned r = (u + 0x7FFFu + ((u >> 16) & 1u)) >> 16;   // RNE
    return (short)r;
}
__device__ __forceinline__ uint32 pk2(float a, float b) {  // v_cvt_pk_bf16_f32
    __hip_bfloat162 h = __float22bfloat162_rn(float2{a, b});
    uint32 r;
    __builtin_memcpy(&r, &h, 4);
    return r;
}
__device__ __forceinline__ int pkfp8x4(float a, float b, float c, float d) {
    int r = __builtin_amdgcn_cvt_pk_fp8_f32(a, b, 0, false);   // bytes 0,1
    r = __builtin_amdgcn_cvt_pk_fp8_f32(c, d, r, true);        // bytes 2,3
    return r;
}
__device__ __forceinline__ unsigned char fp8_1(float a) {
    return (unsigned char)(__builtin_amdgcn_cvt_pk_fp8_f32(a, 0.f, 0, false) & 0xff);
}

// ---- prep: weights -> bf16 A-fragment tiles in d_ws, BIAS FOLDED at c==20 ----
// wAll = 16 tiles x [16 ch][32 c] bf16 (k:0..6, q:7..13, v:14..15).
// Row c=20 of each tile holds the bias (x fragment supplies 1.0 there).
// v weights pre-scaled by 2*log2(e) so tanh needs no input mul in-kernel.
__global__ void prep(const float* __restrict__ Wk, const float* __restrict__ bk,
                     const float* __restrict__ Wq, const float* __restrict__ bq,
                     const float* __restrict__ Wv, const float* __restrict__ bv,
                     short* __restrict__ wkT, short* __restrict__ wqT,
                     short* __restrict__ wvT)
{
    const int t = blockIdx.x * blockDim.x + threadIdx.x;
    if (t < 112 * 32) {
        const int n = t >> 5, c = t & 31;
        float vk = 0.f, vq = 0.f;
        if (n < KQ) {
            if (c < C)       { vk = Wk[c * KQ + n]; vq = Wq[c * KQ + n]; }
            else if (c == C) { vk = bk[n];          vq = bq[n]; }
        }
        wkT[t] = f2bf(vk);
        wqT[t] = f2bf(vq);
        if (t < 32 * 32) {
            const int n2 = t >> 5, c2 = t & 31;
            float vv = 0.f;
            if (n2 < C) {
                if (c2 < C)       vv = Wv[c2 * C + n2] * TWOL2E;
                else if (c2 == C) vv = bv[n2] * TWOL2E;
            }
            wvT[t] = f2bf(vv);
        }
    }
}

// R19 (4th attempt at the R16 confirmation; rounds 17-19 all timed out
// before acquiring a chip). This source is byte-identical to the R16 kernel
// that PASSED at 142.5 us total (absmax 0.078125) — the session's best.
// Evidence base: R16 proved (clock-normalized) that a -24% VALU-issue cut
// gives ~zero cycle gain -> latency/dependency-bound at the 3-barrier
// phase-serialized dataflow and 16-wave/CU LDS cap. All levers measured:
// +TLP -> HBM 3x (R9); LDS-shrink -> bank conflicts (R8/R12); +live regs ->
// spills (R10); -24% VALU -> null (R16). Further gain requires a different
// dataflow (cross-batch pipelining), not scheduling.
__global__ __launch_bounds__(NT, 4) void sa_fused(
    const float* __restrict__ x,
    const short* __restrict__ wAll,
    float* __restrict__ y)
{
    __shared__ __align__(16) unsigned char kp8[T * LDS8];   // k fp8 [i][d] -> later 64*P [i][j]
    __shared__ __align__(16) unsigned char q8 [T * LDS8];   // q fp8 [j][d]
    __shared__ __align__(16) unsigned char vT8[32 * LDS8];  // v^T fp8 [dd][pos] (rows 20..31 = 0)

    const int tid  = threadIdx.x;
    const int lane = tid & 63;
    const int w    = __builtin_amdgcn_readfirstlane(tid >> 6);   // 0..3
    const int quad = lane >> 4;
    const int l16  = lane & 15;
    const int b    = blockIdx.x;
    const float* xb = x + (size_t)b * (T * C);

    // ---- issue x global loads FIRST (both row-tiles; latency overlaps pad) ----
    float4 fA[2], fB[2];
    #pragma unroll
    for (int h = 0; h < 2; ++h) {
        const float* xr = xb + ((w + 4 * h) * 16 + l16) * C;
        fA[h] = (float4){0.f, 0.f, 0.f, 0.f};
        fB[h] = (float4){0.f, 0.f, 0.f, 0.f};
        if (quad < 2) {
            fA[h] = *(const float4*)(xr + quad * 8);
            fB[h] = *(const float4*)(xr + quad * 8 + 4);
        } else if (quad == 2) {
            fA[h] = *(const float4*)(xr + 16);
        }
    }

    // ---- zero pad cols 112..127 of kp8/q8 (d-tail read by score K-loop).
    //      All 256 threads, one uint4 each: tid<128 -> kp8, tid>=128 -> q8. ----
    {
        const uint4 z4 = {0u, 0u, 0u, 0u};
        unsigned char* pb = (tid < T) ? kp8 : q8;
        *(uint4*)&pb[(tid & (T - 1)) * LDS8 + 112] = z4;
    }

    // ---- x fragments (two i-tiles): A[m=l16][k=quad*8+u] == B[k][n=l16];
    //      c pad 20->32, with c=20 element = 1.0 (bias row multiplier) ----
    bf16x8 xf[2];
    #pragma unroll
    for (int h = 0; h < 2; ++h) {
        uint32 p0 = 0, p1 = 0, p2 = 0, p3 = 0;
        if (quad < 2) {
            p0 = pk2(fA[h].x, fA[h].y); p1 = pk2(fA[h].z, fA[h].w);
            p2 = pk2(fB[h].x, fB[h].y); p3 = pk2(fB[h].z, fB[h].w);
        } else if (quad == 2) {
            p0 = pk2(fA[h].x, fA[h].y); p1 = pk2(fA[h].z, fA[h].w);
            p2 = pk2(1.f, 0.f);                       // c=20 -> 1.0 (bias row)
        }
        uint4 u4; u4.x = p0; u4.y = p1; u4.z = p2; u4.w = p3;
        xf[h] = __builtin_bit_cast(bf16x8, u4);
    }

    // ---- projections (bf16 MFMA): wave w owns i-tiles w and w+4. Weight
    //      fragments loaded once per group, used by both tiles. ----
    #pragma unroll
    for (int grp = 0; grp < 4; ++grp) {
        bf16x8 wfr[4];
        #pragma unroll
        for (int t = 0; t < 4; ++t)
            wfr[t] = *(const bf16x8*)(wAll + ((grp * 4 + t) * 16 + l16) * 32 + quad * 8);
        #pragma unroll
        for (int s = 0; s < 4; ++s) {
            const int tt = grp * 4 + s;
            #pragma unroll
            for (int h = 0; h < 2; ++h) {
                const int row = (w + 4 * h) * 16 + l16;
                const f32x4 cc = __builtin_amdgcn_mfma_f32_16x16x32_bf16(
                    wfr[s], xf[h], (f32x4){0.f, 0.f, 0.f, 0.f}, 0, 0, 0);
                if (tt < 14) {                                    // k or q: ELU -> fp8 b32 write
                    // ELU(z) = median(z, e^z-1, 0); muls and -1 adds packed.
                    const f32x2 l2e2 = {LOG2E, LOG2E};
                    const f32x2 m1   = {-1.f, -1.f};
                    f32x2 elo = (f32x2){cc[0], cc[1]} * l2e2;     // v_pk_mul_f32
                    f32x2 ehi = (f32x2){cc[2], cc[3]} * l2e2;
                    elo.x = exp2i(elo.x); elo.y = exp2i(elo.y);
                    ehi.x = exp2i(ehi.x); ehi.y = exp2i(ehi.y);
                    elo += m1; ehi += m1;                         // v_pk_add_f32
                    float e[4];
                    e[0] = __builtin_amdgcn_fmed3f(cc[0], elo.x, 0.f);
                    e[1] = __builtin_amdgcn_fmed3f(cc[1], elo.y, 0.f);
                    e[2] = __builtin_amdgcn_fmed3f(cc[2], ehi.x, 0.f);
                    e[3] = __builtin_amdgcn_fmed3f(cc[3], ehi.y, 0.f);
                    unsigned char* dst = (tt < 7)
                        ? &kp8[row * LDS8 + tt * 16 + quad * 4]
                        : &q8 [row * LDS8 + (tt - 7) * 16 + quad * 4];
                    *(int*)dst = pkfp8x4(e[0], e[1], e[2], e[3]);
                } else {                                          // v: tanh -> vT scatter (b8)
                    #pragma unroll
                    for (int r = 0; r < 4; ++r) {
                        // cc already = 2*log2e*(xWv+bv) via prep pre-scale
                        const float e2 = exp2i(cc[r]);
                        vT8[((tt - 14) * 16 + quad * 4 + r) * LDS8 + row]
                            = fp8_1(fmaf(-2.f, rcpi(e2 + 1.f), 1.f));
                    }
                }
            }
        }
    }
    __syncthreads();

    // ---- scores TRANSPOSED (fp8): S^T = q.k^T. Two j-tiles per wave;
    //      B-operand (k rows) read once, feeds both streams. ----
    f32x4 acc[2][8];
    #pragma unroll
    for (int h = 0; h < 2; ++h)
        #pragma unroll
        for (int nt = 0; nt < 8; ++nt) acc[h][nt] = (f32x4){0.f, 0.f, 0.f, 0.f};
    __builtin_amdgcn_s_setprio(1);
    #pragma unroll
    for (int ks = 0; ks < 4; ++ks) {
        const long a0 = *(const long*)&q8[( w      * 16 + l16) * LDS8 + ks * 32 + quad * 8];
        const long a1 = *(const long*)&q8[((w + 4) * 16 + l16) * LDS8 + ks * 32 + quad * 8];
        #pragma unroll
        for (int nt = 0; nt < 8; ++nt) {
            const long bk8 = *(const long*)&kp8[(nt * 16 + l16) * LDS8 + ks * 32 + quad * 8];
            acc[0][nt] = __builtin_amdgcn_mfma_f32_16x16x32_fp8_fp8(a0, bk8, acc[0][nt], 0, 0, 0);
            acc[1][nt] = __builtin_amdgcn_mfma_f32_16x16x32_fp8_fp8(a1, bk8, acc[1][nt], 0, 0, 0);
        }
    }
    __builtin_amdgcn_s_setprio(0);

    // ---- softmax over i (axis=1), in registers, both j-tiles.
    //      K2E muls and ssum accumulates packed (exp stays scalar TRANS). ----
    float ssum[2][4];
    #pragma unroll
    for (int h = 0; h < 2; ++h) {
        const f32x2 k2e2 = {K2E, K2E};
        f32x2 sa = {0.f, 0.f}, sb = {0.f, 0.f};
        #pragma unroll
        for (int nt = 0; nt < 8; ++nt) {
            f32x2 plo = (f32x2){acc[h][nt][0], acc[h][nt][1]} * k2e2;   // v_pk_mul
            f32x2 phi = (f32x2){acc[h][nt][2], acc[h][nt][3]} * k2e2;
            plo.x = exp2i(plo.x); plo.y = exp2i(plo.y);
            phi.x = exp2i(phi.x); phi.y = exp2i(phi.y);
            acc[h][nt][0] = plo.x; acc[h][nt][1] = plo.y;
            acc[h][nt][2] = phi.x; acc[h][nt][3] = phi.y;
            sa += plo; sb += phi;                                       // v_pk_add
        }
        float st[4] = {sa.x, sa.y, sb.x, sb.y};
        #pragma unroll
        for (int r = 0; r < 4; ++r) {
            float s = st[r];
            s += __shfl_xor(s, 1); s += __shfl_xor(s, 2);
            s += __shfl_xor(s, 4); s += __shfl_xor(s, 8);
            ssum[h][r] = 64.f * rcpi(s);                          // 64*linv[j]
        }
    }
    __syncthreads();                                              // all score reads of kp8/q8 done

    // ---- write 64*P[i][j] fp8 (b32), both tiles; acc*ssum products packed ----
    {
        const f32x2 sA0 = {ssum[0][0], ssum[0][1]}, sB0 = {ssum[0][2], ssum[0][3]};
        const f32x2 sA1 = {ssum[1][0], ssum[1][1]}, sB1 = {ssum[1][2], ssum[1][3]};
        #pragma unroll
        for (int nt = 0; nt < 8; ++nt) {
            const f32x2 p0 = (f32x2){acc[0][nt][0], acc[0][nt][1]} * sA0;
            const f32x2 q0 = (f32x2){acc[0][nt][2], acc[0][nt][3]} * sB0;
            const f32x2 p1 = (f32x2){acc[1][nt][0], acc[1][nt][1]} * sA1;
            const f32x2 q1 = (f32x2){acc[1][nt][2], acc[1][nt][3]} * sB1;
            *(int*)&kp8[(nt * 16 + l16) * LDS8 + w * 16 + quad * 4]
                = pkfp8x4(p0.x, p0.y, q0.x, q0.y);
            *(int*)&kp8[(nt * 16 + l16) * LDS8 + (w + 4) * 16 + quad * 4]
                = pkfp8x4(p1.x, p1.y, q1.x, q1.y);
        }
    }
    __syncthreads();

    // ---- PV (fp8): A = 64P rows (two i-tiles), B = v^T (N = 32, shared) ----
    f32x4 yacc[2][2];
    #pragma unroll
    for (int h = 0; h < 2; ++h) {
        yacc[h][0] = (f32x4){0.f, 0.f, 0.f, 0.f};
        yacc[h][1] = (f32x4){0.f, 0.f, 0.f, 0.f};
    }
    __builtin_amdgcn_s_setprio(1);
    #pragma unroll
    for (int ks = 0; ks < 4; ++ks) {
        const long a0 = *(const long*)&kp8[( w      * 16 + l16) * LDS8 + ks * 32 + quad * 8];
        const long a1 = *(const long*)&kp8[((w + 4) * 16 + l16) * LDS8 + ks * 32 + quad * 8];
        #pragma unroll
        for (int nt = 0; nt < 2; ++nt) {
            const long bv8 = *(const long*)&vT8[(nt * 16 + l16) * LDS8 + ks * 32 + quad * 8];
            yacc[0][nt] = __builtin_amdgcn_mfma_f32_16x16x32_fp8_fp8(a0, bv8, yacc[0][nt], 0, 0, 0);
            yacc[1][nt] = __builtin_amdgcn_mfma_f32_16x16x32_fp8_fp8(a1, bv8, yacc[1][nt], 0, 0, 0);
        }
    }
    __builtin_amdgcn_s_setprio(0);

    // ---- epilogue: y = PV/64 + x (direct stores, R7-known-good) ----
    {
        float* yb = y + (size_t)b * (T * C);
        const float inv64 = 1.f / 64.f;
        #pragma unroll
        for (int h = 0; h < 2; ++h)
            #pragma unroll
            for (int r = 0; r < 4; ++r) {
                const int row  = (w + 4 * h) * 16 + quad * 4 + r;
                const int base = row * C;
                yb[base + l16] = yacc[h][0][r] * inv64 + xb[base + l16];
                if (l16 < 4)
                    yb[base + 16 + l16] = yacc[h][1][r] * inv64 + xb[base + 16 + l16];
            }
    }
}

extern "C" void kernel_launch(void* const* d_in, const int* in_sizes, int n_in,
                              void* d_out, int out_size, void* d_ws, size_t ws_size,
                              hipStream_t stream) {
    const float* x  = (const float*)d_in[0];
    const float* Wk = (const float*)d_in[1];
    const float* bk = (const float*)d_in[2];
    const float* Wq = (const float*)d_in[3];
    const float* bq = (const float*)d_in[4];
    const float* Wv = (const float*)d_in[5];
    const float* bv = (const float*)d_in[6];
    float* y = (float*)d_out;

    char* ws = (char*)d_ws;
    short* wkT = (short*)ws;                 // tiles 0..6   [112][32] bf16 (bias at c=20)
    short* wqT = (short*)(ws + 7168);        // tiles 7..13  [112][32] bf16
    short* wvT = (short*)(ws + 14336);       // tiles 14..15 [32][32]  bf16 (pre-scaled 2log2e)

    prep<<<14, 256, 0, stream>>>(Wk, bk, Wq, bq, Wv, bv, wkT, wqT, wvT);

    const int B = in_sizes[0] / (T * C);     // 4096
    sa_fused<<<B, NT, 0, stream>>>(x, (const short*)ws, y);
}